// Round 6
// baseline (556.265 us; speedup 1.0000x reference)
//
#include <hip/hip_runtime.h>
#include <math.h>

#define H 4096
#define E 64
#define TOPK 8
#define NK (H / 32)          // 128 MFMA k-steps
#define TAU 1e-4f            // 4-pass split-bf16 == f32-FMA accuracy class (r1-r5 validated)

// Fused MoE router, round-6: barrier-free direct-global MFMA GEMM.
//   Round-5 post-mortem: 1 block/CU + per-tile barrier vmcnt(0) drain -> 74%
//   stall (MfmaUtil 8%, VALUBusy 12%). Fix: A has no cross-wave reuse and W
//   (1 MB) is L2-resident -> drop K-loop LDS + barriers entirely; lanes load
//   MFMA fragments directly from global (A: 32 B/lane f32 -> in-reg bf16
//   hi/lo split, bit-identical to r5's validated path; W: 16 B/lane uint4).
//   Parity double-buffer prefetch (distance 2). Wave = 16 rows x 32 experts;
//   block = 128 thr (2 waves = full E); grid = T/16 = 1024 -> 8 waves/CU in
//   4 independent blocks. One barrier total (epilogue).
//   k0: W f32 -> Whi/Wlo bf16 workspace (1 MB, L2-resident)
//   k1: gemm + bias + sigmoid + probs + top-9 + TAU flag
//   k2: exact-f64 recheck of flagged rows (~150 at TAU=1e-4)
// Workspace: [0,512K) Whi ; [512K,1M) Wlo ; [1M] flagcnt ; [1M+16,..) flaglist.

typedef __attribute__((ext_vector_type(8))) short bf16x8;
typedef __attribute__((ext_vector_type(4))) float f32x4;

__device__ __forceinline__ unsigned short bf16_rne(float x) {
    unsigned int u = __float_as_uint(x);
    u += 0x7FFFu + ((u >> 16) & 1u);
    return (unsigned short)(u >> 16);
}
__device__ __forceinline__ float bf16_f32(unsigned short h) {
    return __uint_as_float(((unsigned int)h) << 16);
}

// pack two f32 into bf16x2 hi + bf16x2 lo dwords
#define SPLIT2(F0, F1, HI, LO)                                          \
    {                                                                   \
        const unsigned short h0 = bf16_rne(F0), h1 = bf16_rne(F1);      \
        const unsigned short l0 = bf16_rne((F0) - bf16_f32(h0));        \
        const unsigned short l1 = bf16_rne((F1) - bf16_f32(h1));        \
        HI = (unsigned int)h0 | ((unsigned int)h1 << 16);               \
        LO = (unsigned int)l0 | ((unsigned int)l1 << 16);               \
    }

// ---------------- kernel 0: W f32 -> bf16 hi/lo split ----------------
__global__ __launch_bounds__(256) void w_split(
    const float* __restrict__ W, unsigned short* __restrict__ Whi,
    unsigned short* __restrict__ Wlo)
{
    const size_t t = (size_t)blockIdx.x * 256 + threadIdx.x;  // 65536 threads x 4
    const float4 v = *(const float4*)(W + t * 4);
    uint2 h, l;
    SPLIT2(v.x, v.y, h.x, l.x);
    SPLIT2(v.z, v.w, h.y, l.y);
    *(uint2*)(Whi + t * 4) = h;
    *(uint2*)(Wlo + t * 4) = l;
}

// ---------------- kernel 1: direct-global split-bf16 MFMA + fused topk ----------------
// one k-step body: split A regs -> fragments, issue reload for step TN, 8 MFMA.
// (value-copies of the W regs keep old values live past the reload issue)
#define KSTEP(A0, A1, BH0, BL0, BH1, BL1, TN)                              \
    {                                                                      \
        uint4 h_, lo_;                                                     \
        SPLIT2((A0).x, (A0).y, h_.x, lo_.x);                               \
        SPLIT2((A0).z, (A0).w, h_.y, lo_.y);                               \
        SPLIT2((A1).x, (A1).y, h_.z, lo_.z);                               \
        SPLIT2((A1).z, (A1).w, h_.w, lo_.w);                               \
        const bf16x8 fah  = *(const bf16x8*)&h_;                           \
        const bf16x8 fal  = *(const bf16x8*)&lo_;                          \
        const uint4 ch0 = BH0, cl0 = BL0, ch1 = BH1, cl1 = BL1;            \
        if ((TN) < NK) {                                                   \
            const int kn = (TN) * 32;                                      \
            A0  = *(const float4*)(ap + kn);                               \
            A1  = *(const float4*)(ap + kn + 4);                           \
            BH0 = *(const uint4*)(wh0 + kn);                               \
            BL0 = *(const uint4*)(wl0 + kn);                               \
            BH1 = *(const uint4*)(wh1 + kn);                               \
            BL1 = *(const uint4*)(wl1 + kn);                               \
        }                                                                  \
        const bf16x8 fbh0 = *(const bf16x8*)&ch0;                          \
        const bf16x8 fbl0 = *(const bf16x8*)&cl0;                          \
        const bf16x8 fbh1 = *(const bf16x8*)&ch1;                          \
        const bf16x8 fbl1 = *(const bf16x8*)&cl1;                          \
        acc0 = __builtin_amdgcn_mfma_f32_16x16x32_bf16(fah, fbh0, acc0, 0, 0, 0); \
        acc0 = __builtin_amdgcn_mfma_f32_16x16x32_bf16(fah, fbl0, acc0, 0, 0, 0); \
        acc0 = __builtin_amdgcn_mfma_f32_16x16x32_bf16(fal, fbh0, acc0, 0, 0, 0); \
        acc0 = __builtin_amdgcn_mfma_f32_16x16x32_bf16(fal, fbl0, acc0, 0, 0, 0); \
        acc1 = __builtin_amdgcn_mfma_f32_16x16x32_bf16(fah, fbh1, acc1, 0, 0, 0); \
        acc1 = __builtin_amdgcn_mfma_f32_16x16x32_bf16(fah, fbl1, acc1, 0, 0, 0); \
        acc1 = __builtin_amdgcn_mfma_f32_16x16x32_bf16(fal, fbh1, acc1, 0, 0, 0); \
        acc1 = __builtin_amdgcn_mfma_f32_16x16x32_bf16(fal, fbl1, acc1, 0, 0, 0); \
    }

__global__ __launch_bounds__(128, 2) void router_gemm_topk(
    const float* __restrict__ A, const unsigned short* __restrict__ Whi,
    const unsigned short* __restrict__ Wlo, const float* __restrict__ bias,
    float* __restrict__ weights, float* __restrict__ indices,
    float* __restrict__ probs,
    int* __restrict__ flagcnt, int* __restrict__ flaglist, int cap)
{
    __shared__ float Llds[16][E + 1];        // f32 logits for topk (4.2 KB)

    const int tid   = threadIdx.x;
    const int wv    = tid >> 6;          // expert half 0..1
    const int l     = tid & 63;
    const int lrow  = l & 15;            // A row / B expert within tile
    const int khalf = l >> 4;            // 8-elem k-group within 32-k step
    const int cbase = wv * 32;
    const long row0 = (long)blockIdx.x * 16;

    // per-lane fragment base pointers (validated r5 lane->(row,k) mapping)
    const float* __restrict__ ap =
        A + (row0 + lrow) * H + khalf * 8;
    const unsigned short* __restrict__ wh0 = Whi + (size_t)(cbase + lrow) * H + khalf * 8;
    const unsigned short* __restrict__ wl0 = Wlo + (size_t)(cbase + lrow) * H + khalf * 8;
    const unsigned short* __restrict__ wh1 = Whi + (size_t)(cbase + 16 + lrow) * H + khalf * 8;
    const unsigned short* __restrict__ wl1 = Wlo + (size_t)(cbase + 16 + lrow) * H + khalf * 8;

    f32x4 acc0 = {0.f, 0.f, 0.f, 0.f};
    f32x4 acc1 = {0.f, 0.f, 0.f, 0.f};

    // parity double-buffer prefetch: slot X = even steps, slot Y = odd steps
    float4 a0X = *(const float4*)(ap + 0);
    float4 a1X = *(const float4*)(ap + 4);
    uint4  h0X = *(const uint4*)(wh0);
    uint4  l0X = *(const uint4*)(wl0);
    uint4  h1X = *(const uint4*)(wh1);
    uint4  l1X = *(const uint4*)(wl1);
    float4 a0Y = *(const float4*)(ap + 32);
    float4 a1Y = *(const float4*)(ap + 36);
    uint4  h0Y = *(const uint4*)(wh0 + 32);
    uint4  l0Y = *(const uint4*)(wl0 + 32);
    uint4  h1Y = *(const uint4*)(wh1 + 32);
    uint4  l1Y = *(const uint4*)(wl1 + 32);

    for (int t = 0; t < NK; t += 2) {
        KSTEP(a0X, a1X, h0X, l0X, h1X, l1X, t + 2)   // consume even, reload t+2
        KSTEP(a0Y, a1Y, h0Y, l0Y, h1Y, l1Y, t + 3)   // consume odd,  reload t+3
    }

    // ---- epilogue: logits (+bias) -> LDS (C/D: row = khalf*4 + reg) ----
    {
        const int c0 = cbase + lrow;
        const int c1 = cbase + 16 + lrow;
        const float b0 = bias[c0], b1 = bias[c1];
#pragma unroll
        for (int r = 0; r < 4; ++r) {
            const int row = khalf * 4 + r;
            Llds[row][c0] = acc0[r] + b0;
            Llds[row][c1] = acc1[r] + b1;
        }
    }
    __syncthreads();

    // coalesced probs write: row = tid>>3 (0..15), 8 experts per thread
    {
        const int row = tid >> 3;
        const int c   = (tid & 7) * 8;
        float4 o0, o1;
        o0.x = 1.0f / (1.0f + __expf(-Llds[row][c + 0]));
        o0.y = 1.0f / (1.0f + __expf(-Llds[row][c + 1]));
        o0.z = 1.0f / (1.0f + __expf(-Llds[row][c + 2]));
        o0.w = 1.0f / (1.0f + __expf(-Llds[row][c + 3]));
        o1.x = 1.0f / (1.0f + __expf(-Llds[row][c + 4]));
        o1.y = 1.0f / (1.0f + __expf(-Llds[row][c + 5]));
        o1.z = 1.0f / (1.0f + __expf(-Llds[row][c + 6]));
        o1.w = 1.0f / (1.0f + __expf(-Llds[row][c + 7]));
        *(float4*)(probs + (row0 + row) * E + c + 0) = o0;
        *(float4*)(probs + (row0 + row) * E + c + 4) = o1;
    }

    // top-9 per row (threads 0..15); strict > => lowest idx on ties
    if (tid < 16) {
        const int r = tid;
        unsigned long long taken = 0ull;
        float sv[TOPK + 1];
        int   si[TOPK + 1];
#pragma unroll
        for (int it = 0; it <= TOPK; ++it) {
            float best = -3.0e38f;
            int   bi   = 0;
            for (int j = 0; j < E; ++j) {
                if (!((taken >> j) & 1ull)) {
                    const float v = Llds[r][j];
                    if (v > best) { best = v; bi = j; }
                }
            }
            taken |= 1ull << bi;
            sv[it] = best;
            si[it] = bi;
        }
        float w8[TOPK];
        float sum = 0.0f;
#pragma unroll
        for (int it = 0; it < TOPK; ++it) {
            w8[it] = 1.0f / (1.0f + __expf(-sv[it]));
            sum += w8[it];
        }
        const float inv = 1.0f / sum;
#pragma unroll
        for (int it = 0; it < TOPK; ++it) {
            weights[(row0 + r) * TOPK + it] = w8[it] * inv;
            indices[(row0 + r) * TOPK + it] = (float)si[it];
        }
        bool amb = false;
#pragma unroll
        for (int it = 0; it < TOPK; ++it) amb |= (sv[it] - sv[it + 1]) < TAU;
        if (amb && cap > 0) {
            const int pos = atomicAdd(flagcnt, 1);
            if (pos < cap) flaglist[pos] = (int)(row0 + r);
        }
    }
}

// ---------------- kernel 2: exact-f64 recheck of flagged rows ----------------
__global__ __launch_bounds__(256) void router_recheck(
    const float* __restrict__ A, const float* __restrict__ W,
    const float* __restrict__ bias,
    float* __restrict__ weights, float* __restrict__ indices,
    const int* __restrict__ flagcnt, const int* __restrict__ flaglist,
    int cap)
{
    __shared__ double part[4][E];
    __shared__ double lg[E];

    const int e  = threadIdx.x & 63;   // expert
    const int kc = threadIdx.x >> 6;   // k-chunk 0..3

    int n = *flagcnt;
    if (n > cap) n = cap;

    for (int f = blockIdx.x; f < n; f += gridDim.x) {
        const int row = flaglist[f];
        const float* ar = A + (long)row * H + kc * (H / 4);
        const float* wr = W + (long)e   * H + kc * (H / 4);
        double s = 0.0;
        for (int k = 0; k < H / 4; k += 4) {
            const float4 av = *(const float4*)(ar + k);
            const float4 wv = *(const float4*)(wr + k);
            s = fma((double)av.x, (double)wv.x, s);
            s = fma((double)av.y, (double)wv.y, s);
            s = fma((double)av.z, (double)wv.z, s);
            s = fma((double)av.w, (double)wv.w, s);
        }
        part[kc][e] = s;
        __syncthreads();
        if (threadIdx.x < E) {
            const int j = threadIdx.x;
            lg[j] = ((part[0][j] + part[1][j]) + (part[2][j] + part[3][j]))
                    + (double)bias[j];
        }
        __syncthreads();
        if (threadIdx.x == 0) {
            unsigned long long taken = 0ull;
            float wsel[TOPK];
            int   isel[TOPK];
            float psum = 0.0f;
            for (int it = 0; it < TOPK; ++it) {
                double best = -1.0e300;
                int    bi   = 0;
                for (int j = 0; j < E; ++j) {
                    if (!((taken >> j) & 1ull)) {
                        const double v = lg[j];
                        if (v > best) { best = v; bi = j; }
                    }
                }
                taken |= 1ull << bi;
                const float p = 1.0f / (1.0f + __expf(-(float)best));
                wsel[it] = p;
                isel[it] = bi;
                psum += p;
            }
            const float inv = 1.0f / psum;
            for (int it = 0; it < TOPK; ++it) {
                weights[(long)row * TOPK + it] = wsel[it] * inv;
                indices[(long)row * TOPK + it] = (float)isel[it];
            }
        }
        __syncthreads();
    }
}

extern "C" void kernel_launch(void* const* d_in, const int* in_sizes, int n_in,
                              void* d_out, int out_size, void* d_ws, size_t ws_size,
                              hipStream_t stream)
{
    const float* A    = (const float*)d_in[0];   // [T, H]
    const float* W    = (const float*)d_in[1];   // [E, H]
    const float* bias = (const float*)d_in[2];   // [E]
    const int T = in_sizes[0] / H;               // 16384

    float* out     = (float*)d_out;
    float* weights = out;                          // [T, 8]
    float* indices = out + (size_t)T * TOPK;       // [T, 8] (float-valued)
    float* probs   = out + (size_t)T * 2 * TOPK;   // [T, 64]

    unsigned short* Whi = (unsigned short*)d_ws;           // 512 KB
    unsigned short* Wlo = Whi + (size_t)E * H;             // 512 KB
    const size_t W_BYTES = (size_t)E * H * 2 * sizeof(unsigned short);
    int* flagcnt  = (int*)((char*)d_ws + W_BYTES);
    int* flaglist = flagcnt + 4;
    long cap_l = ((long)ws_size - (long)W_BYTES - 16) / 4;
    int  cap   = cap_l < 0 ? 0 : (cap_l > T ? T : (int)cap_l);

    if (cap > 0) hipMemsetAsync(flagcnt, 0, sizeof(int), stream);

    w_split<<<(E * H / 4) / 256, 256, 0, stream>>>(W, Whi, Wlo);
    router_gemm_topk<<<T / 16, 128, 0, stream>>>(A, Whi, Wlo, bias,
                                                 weights, indices, probs,
                                                 flagcnt, flaglist, cap);
    if (cap > 0)
        router_recheck<<<256, 256, 0, stream>>>(A, W, bias, weights, indices,
                                                flagcnt, flaglist, cap);
}

// Round 7
// 489.180 us; speedup vs baseline: 1.1371x; 1.1371x over previous
//
#include <hip/hip_runtime.h>
#include <math.h>

#define H 4096
#define E 64
#define TOPK 8
#define BM 16               // rows per block
#define BK 64               // K-tile
#define NTILE (H / BK)      // 64
#define TAU 1e-4f           // 4-pass split-bf16 == f32-FMA accuracy class (r1-r6 validated)

// Fused MoE router, round-7: r5 structure, occupancy-fixed geometry.
//   r5 post-mortem: 1 block/CU -> every per-tile barrier vmcnt(0) drain stalls
//   the whole CU (74% idle). r6 (no-LDS direct global) was worse: scattered
//   per-lane W loads are txn-issue-bound. Fix: keep r5's coalesced LDS staging
//   + swizzle + bit-exact split, shrink to BM=16 / 256 thr / 24 KB LDS ->
//   grid 1024 = 4 independent blocks per CU (16 waves/CU): other blocks cover
//   each block's barrier drains.
//   k0: W f32 -> Whi/Wlo bf16 workspace (1 MB, L2-resident)
//   k1: 4-pass split-bf16 MFMA gemm + bias + sigmoid + probs + top-9 + flag
//   k2: exact-f64 recheck of flagged rows (~150 at TAU=1e-4)
// Workspace: [0,512K) Whi ; [512K,1M) Wlo ; [1M] flagcnt ; [1M+16,..) flaglist.

typedef __attribute__((ext_vector_type(8))) short bf16x8;
typedef __attribute__((ext_vector_type(4))) float f32x4;

__device__ __forceinline__ unsigned short bf16_rne(float x) {
    unsigned int u = __float_as_uint(x);
    u += 0x7FFFu + ((u >> 16) & 1u);
    return (unsigned short)(u >> 16);
}
__device__ __forceinline__ float bf16_f32(unsigned short h) {
    return __uint_as_float(((unsigned int)h) << 16);
}

// pack two f32 into bf16x2 hi + bf16x2 lo dwords
#define SPLIT2(F0, F1, HI, LO)                                          \
    {                                                                   \
        const unsigned short h0 = bf16_rne(F0), h1 = bf16_rne(F1);      \
        const unsigned short l0 = bf16_rne((F0) - bf16_f32(h0));        \
        const unsigned short l1 = bf16_rne((F1) - bf16_f32(h1));        \
        HI = (unsigned int)h0 | ((unsigned int)h1 << 16);               \
        LO = (unsigned int)l0 | ((unsigned int)l1 << 16);               \
    }

// ---------------- kernel 0: W f32 -> bf16 hi/lo split ----------------
__global__ __launch_bounds__(256) void w_split(
    const float* __restrict__ W, unsigned short* __restrict__ Whi,
    unsigned short* __restrict__ Wlo)
{
    const size_t t = (size_t)blockIdx.x * 256 + threadIdx.x;  // 65536 threads x 4
    const float4 v = *(const float4*)(W + t * 4);
    uint2 h, l;
    SPLIT2(v.x, v.y, h.x, l.x);
    SPLIT2(v.z, v.w, h.y, l.y);
    *(uint2*)(Whi + t * 4) = h;
    *(uint2*)(Wlo + t * 4) = l;
}

// ---------------- kernel 1: split-bf16 MFMA GEMM + fused topk ----------------
__global__ __launch_bounds__(256, 4) void router_gemm_topk(
    const float* __restrict__ A, const unsigned short* __restrict__ Whi,
    const unsigned short* __restrict__ Wlo, const float* __restrict__ bias,
    float* __restrict__ weights, float* __restrict__ indices,
    float* __restrict__ probs,
    int* __restrict__ flagcnt, int* __restrict__ flaglist, int cap)
{
    // 16B-slot XOR swizzle (slot ^ (row&7)) on both write and read sides
    // (r5-validated): breaks the 128B-row-stride bank alias on frag reads.
    __shared__ unsigned short Ahi[BM][BK];   // 2 KB
    __shared__ unsigned short Alo[BM][BK];   // 2 KB
    __shared__ unsigned short Bhi[E][BK];    // 8 KB
    __shared__ unsigned short Blo[E][BK];    // 8 KB
    __shared__ float Llds[BM][E + 1];        // 4.2 KB

    const int tid = threadIdx.x;
    const long row0 = (long)blockIdx.x * BM;

    // ---- A staging map (threads 0..127): row = tid>>3, 8-f32 seg = tid&7
    const int arow  = tid >> 3;
    const int aseg  = tid & 7;
    const int aslot = (aseg ^ (arow & 7)) * 8;           // ushort offset
    // ---- W staging map (all 256): expert = tid>>2, two 16B slots
    const int wrow  = tid >> 2;
    const int wseg  = (tid & 3) * 2;
    const int wslot0 = ((wseg + 0) ^ (wrow & 7)) * 8;
    const int wslot1 = ((wseg + 1) ^ (wrow & 7)) * 8;

    const float* __restrict__ ap          = A   + (row0 + arow) * H + aseg * 8;
    const unsigned short* __restrict__ wh = Whi + (size_t)wrow * H + wseg * 8;
    const unsigned short* __restrict__ wl = Wlo + (size_t)wrow * H + wseg * 8;

    // ---- compute map: 4 waves; wave wv = 16 rows x experts [wv*16, wv*16+16)
    const int wv    = tid >> 6;
    const int l     = tid & 63;
    const int lrow  = l & 15;
    const int khalf = l >> 4;            // 8-elem k-group within 32-k step

    f32x4 acc = {0.f, 0.f, 0.f, 0.f};

    // ---- prologue: prefetch tile 0 into registers
    float4 pa0, pa1;
    if (tid < 128) {
        pa0 = *(const float4*)(ap + 0);
        pa1 = *(const float4*)(ap + 4);
    }
    uint4 pwh0 = *(const uint4*)(wh + 0);
    uint4 pwh1 = *(const uint4*)(wh + 8);
    uint4 pwl0 = *(const uint4*)(wl + 0);
    uint4 pwl1 = *(const uint4*)(wl + 8);

    for (int t = 0; t < NTILE; ++t) {
        // split A to bf16 hi/lo and store staged tile
        if (tid < 128) {
            uint4 h, lo;
            SPLIT2(pa0.x, pa0.y, h.x, lo.x);
            SPLIT2(pa0.z, pa0.w, h.y, lo.y);
            SPLIT2(pa1.x, pa1.y, h.z, lo.z);
            SPLIT2(pa1.z, pa1.w, h.w, lo.w);
            *(uint4*)(&Ahi[arow][aslot]) = h;
            *(uint4*)(&Alo[arow][aslot]) = lo;
        }
        *(uint4*)(&Bhi[wrow][wslot0]) = pwh0;
        *(uint4*)(&Bhi[wrow][wslot1]) = pwh1;
        *(uint4*)(&Blo[wrow][wslot0]) = pwl0;
        *(uint4*)(&Blo[wrow][wslot1]) = pwl1;
        __syncthreads();

        // issue next-tile loads; they stay in flight across the MFMA block
        if (t + 1 < NTILE) {
            const int kn = (t + 1) * BK;
            if (tid < 128) {
                pa0 = *(const float4*)(ap + kn + 0);
                pa1 = *(const float4*)(ap + kn + 4);
            }
            pwh0 = *(const uint4*)(wh + kn + 0);
            pwh1 = *(const uint4*)(wh + kn + 8);
            pwl0 = *(const uint4*)(wl + kn + 0);
            pwl1 = *(const uint4*)(wl + kn + 8);
        }

#pragma unroll
        for (int s = 0; s < BK / 32; ++s) {
            const int fs = ((s * 4 + khalf) ^ (lrow & 7)) * 8;
            const bf16x8 fah = *(const bf16x8*)(&Ahi[lrow][fs]);
            const bf16x8 fal = *(const bf16x8*)(&Alo[lrow][fs]);
            const bf16x8 fbh = *(const bf16x8*)(&Bhi[wv * 16 + lrow][fs]);
            const bf16x8 fbl = *(const bf16x8*)(&Blo[wv * 16 + lrow][fs]);
            acc = __builtin_amdgcn_mfma_f32_16x16x32_bf16(fah, fbh, acc, 0, 0, 0);
            acc = __builtin_amdgcn_mfma_f32_16x16x32_bf16(fah, fbl, acc, 0, 0, 0);
            acc = __builtin_amdgcn_mfma_f32_16x16x32_bf16(fal, fbh, acc, 0, 0, 0);
            acc = __builtin_amdgcn_mfma_f32_16x16x32_bf16(fal, fbl, acc, 0, 0, 0);
        }
        __syncthreads();
    }

    // ---- epilogue: logits (+bias) -> LDS (C/D: col=lane&15, row=khalf*4+reg)
    {
        const int c = wv * 16 + lrow;
        const float b = bias[c];
#pragma unroll
        for (int r = 0; r < 4; ++r)
            Llds[khalf * 4 + r][c] = acc[r] + b;
    }
    __syncthreads();

    // coalesced probs write: row = tid>>4 (0..15), 4 experts per thread
    {
        const int row = tid >> 4;
        const int c   = (tid & 15) * 4;
        float4 o;
        o.x = 1.0f / (1.0f + __expf(-Llds[row][c + 0]));
        o.y = 1.0f / (1.0f + __expf(-Llds[row][c + 1]));
        o.z = 1.0f / (1.0f + __expf(-Llds[row][c + 2]));
        o.w = 1.0f / (1.0f + __expf(-Llds[row][c + 3]));
        *(float4*)(probs + (row0 + row) * E + c) = o;
    }

    // top-9 per row (threads 0..15); strict > => lowest idx on ties
    if (tid < BM) {
        const int r = tid;
        unsigned long long taken = 0ull;
        float sv[TOPK + 1];
        int   si[TOPK + 1];
#pragma unroll
        for (int it = 0; it <= TOPK; ++it) {
            float best = -3.0e38f;
            int   bi   = 0;
            for (int j = 0; j < E; ++j) {
                if (!((taken >> j) & 1ull)) {
                    const float v = Llds[r][j];
                    if (v > best) { best = v; bi = j; }
                }
            }
            taken |= 1ull << bi;
            sv[it] = best;
            si[it] = bi;
        }
        float w8[TOPK];
        float sum = 0.0f;
#pragma unroll
        for (int it = 0; it < TOPK; ++it) {
            w8[it] = 1.0f / (1.0f + __expf(-sv[it]));
            sum += w8[it];
        }
        const float inv = 1.0f / sum;
#pragma unroll
        for (int it = 0; it < TOPK; ++it) {
            weights[(row0 + r) * TOPK + it] = w8[it] * inv;
            indices[(row0 + r) * TOPK + it] = (float)si[it];
        }
        bool amb = false;
#pragma unroll
        for (int it = 0; it < TOPK; ++it) amb |= (sv[it] - sv[it + 1]) < TAU;
        if (amb && cap > 0) {
            const int pos = atomicAdd(flagcnt, 1);
            if (pos < cap) flaglist[pos] = (int)(row0 + r);
        }
    }
}

// ---------------- kernel 2: exact-f64 recheck of flagged rows ----------------
__global__ __launch_bounds__(256) void router_recheck(
    const float* __restrict__ A, const float* __restrict__ W,
    const float* __restrict__ bias,
    float* __restrict__ weights, float* __restrict__ indices,
    const int* __restrict__ flagcnt, const int* __restrict__ flaglist,
    int cap)
{
    __shared__ double part[4][E];
    __shared__ double lg[E];

    const int e  = threadIdx.x & 63;   // expert
    const int kc = threadIdx.x >> 6;   // k-chunk 0..3

    int n = *flagcnt;
    if (n > cap) n = cap;

    for (int f = blockIdx.x; f < n; f += gridDim.x) {
        const int row = flaglist[f];
        const float* ar = A + (long)row * H + kc * (H / 4);
        const float* wr = W + (long)e   * H + kc * (H / 4);
        double s = 0.0;
        for (int k = 0; k < H / 4; k += 4) {
            const float4 av = *(const float4*)(ar + k);
            const float4 wv = *(const float4*)(wr + k);
            s = fma((double)av.x, (double)wv.x, s);
            s = fma((double)av.y, (double)wv.y, s);
            s = fma((double)av.z, (double)wv.z, s);
            s = fma((double)av.w, (double)wv.w, s);
        }
        part[kc][e] = s;
        __syncthreads();
        if (threadIdx.x < E) {
            const int j = threadIdx.x;
            lg[j] = ((part[0][j] + part[1][j]) + (part[2][j] + part[3][j]))
                    + (double)bias[j];
        }
        __syncthreads();
        if (threadIdx.x == 0) {
            unsigned long long taken = 0ull;
            float wsel[TOPK];
            int   isel[TOPK];
            float psum = 0.0f;
            for (int it = 0; it < TOPK; ++it) {
                double best = -1.0e300;
                int    bi   = 0;
                for (int j = 0; j < E; ++j) {
                    if (!((taken >> j) & 1ull)) {
                        const double v = lg[j];
                        if (v > best) { best = v; bi = j; }
                    }
                }
                taken |= 1ull << bi;
                const float p = 1.0f / (1.0f + __expf(-(float)best));
                wsel[it] = p;
                isel[it] = bi;
                psum += p;
            }
            const float inv = 1.0f / psum;
            for (int it = 0; it < TOPK; ++it) {
                weights[(long)row * TOPK + it] = wsel[it] * inv;
                indices[(long)row * TOPK + it] = (float)isel[it];
            }
        }
        __syncthreads();
    }
}

extern "C" void kernel_launch(void* const* d_in, const int* in_sizes, int n_in,
                              void* d_out, int out_size, void* d_ws, size_t ws_size,
                              hipStream_t stream)
{
    const float* A    = (const float*)d_in[0];   // [T, H]
    const float* W    = (const float*)d_in[1];   // [E, H]
    const float* bias = (const float*)d_in[2];   // [E]
    const int T = in_sizes[0] / H;               // 16384

    float* out     = (float*)d_out;
    float* weights = out;                          // [T, 8]
    float* indices = out + (size_t)T * TOPK;       // [T, 8] (float-valued)
    float* probs   = out + (size_t)T * 2 * TOPK;   // [T, 64]

    unsigned short* Whi = (unsigned short*)d_ws;           // 512 KB
    unsigned short* Wlo = Whi + (size_t)E * H;             // 512 KB
    const size_t W_BYTES = (size_t)E * H * 2 * sizeof(unsigned short);
    int* flagcnt  = (int*)((char*)d_ws + W_BYTES);
    int* flaglist = flagcnt + 4;
    long cap_l = ((long)ws_size - (long)W_BYTES - 16) / 4;
    int  cap   = cap_l < 0 ? 0 : (cap_l > T ? T : (int)cap_l);

    if (cap > 0) hipMemsetAsync(flagcnt, 0, sizeof(int), stream);

    w_split<<<(E * H / 4) / 256, 256, 0, stream>>>(W, Whi, Wlo);
    router_gemm_topk<<<T / BM, 256, 0, stream>>>(A, Whi, Wlo, bias,
                                                 weights, indices, probs,
                                                 flagcnt, flaglist, cap);
    if (cap > 0)
        router_recheck<<<256, 256, 0, stream>>>(A, W, bias, weights, indices,
                                                flagcnt, flaglist, cap);
}